// Round 1
// baseline (28592.834 us; speedup 1.0000x reference)
//
#include <hip/hip_runtime.h>
#include <stdint.h>

#define S_LEN 8192
#define DIM   2048
#define W2    4096   // W row length = 2*DIM

typedef __attribute__((ext_vector_type(8))) __bf16 bf16x8;
typedef __attribute__((ext_vector_type(4))) float  floatx4;
typedef unsigned long long u64;
typedef unsigned int       u32;

// ---------------------------------------------------------------------------
// Init: tag buffers. buf0 = s_0 = -1.0 with tag 0; buf1 tag 0 (never matches
// its first expected tag 1, so readers spin until written).
// ---------------------------------------------------------------------------
__global__ void init_pairs(u64* __restrict__ pairs) {
  int i = blockIdx.x * 256 + threadIdx.x;
  if (i < 2 * DIM) {
    pairs[i] = ((u64)__float_as_uint(-1.0f) << 32) | 0ull;
  }
}

// ---------------------------------------------------------------------------
// GEMM: C[m][n] = sum_k A[m][k] * W[n*4096 + 2048 + k] + b[n]
// A: context_enc (8192 x 2048) f32 row-major. C written into d_out rows.
// bf16 MFMA 16x16x32, 64x64 tile, 4 waves each computing a 32x32 quadrant.
// ---------------------------------------------------------------------------
__device__ inline bf16x8 pack_bf8(float4 a, float4 b) {
  bf16x8 h;
  h[0] = (__bf16)a.x; h[1] = (__bf16)a.y; h[2] = (__bf16)a.z; h[3] = (__bf16)a.w;
  h[4] = (__bf16)b.x; h[5] = (__bf16)b.y; h[6] = (__bf16)b.z; h[7] = (__bf16)b.w;
  return h;
}

__global__ __launch_bounds__(256) void gemm_ctx(const float* __restrict__ A,
                                                const float* __restrict__ W,
                                                const float* __restrict__ bias,
                                                float* __restrict__ C) {
  __shared__ __bf16 As[64][72];   // +8 pad: 144B rows keep 16B alignment, kill conflicts
  __shared__ __bf16 Bs[64][72];
  const int tid  = threadIdx.x;
  const int m0   = blockIdx.y * 64;
  const int n0   = blockIdx.x * 64;
  const int w    = tid >> 6;           // wave 0..3
  const int lane = tid & 63;
  const int wm   = w >> 1, wn = w & 1; // 2x2 wave grid of 32x32 tiles
  const int r    = tid >> 2;           // staging row 0..63
  const int seg  = tid & 3;            // 16-float segment

  floatx4 acc[2][2] = {};

  for (int k0 = 0; k0 < DIM; k0 += 64) {
    { // stage A and B tiles (fp32 -> bf16)
      const float* pa = A + (size_t)(m0 + r) * DIM + k0 + seg * 16;
      const float* pb = W + (size_t)(n0 + r) * W2 + DIM + k0 + seg * 16;
      float4 a0 = ((const float4*)pa)[0], a1 = ((const float4*)pa)[1];
      float4 a2 = ((const float4*)pa)[2], a3 = ((const float4*)pa)[3];
      float4 b0 = ((const float4*)pb)[0], b1 = ((const float4*)pb)[1];
      float4 b2 = ((const float4*)pb)[2], b3 = ((const float4*)pb)[3];
      *(bf16x8*)&As[r][seg * 16]     = pack_bf8(a0, a1);
      *(bf16x8*)&As[r][seg * 16 + 8] = pack_bf8(a2, a3);
      *(bf16x8*)&Bs[r][seg * 16]     = pack_bf8(b0, b1);
      *(bf16x8*)&Bs[r][seg * 16 + 8] = pack_bf8(b2, b3);
    }
    __syncthreads();
    #pragma unroll
    for (int kk = 0; kk < 64; kk += 32) {
      const int ks = kk + (lane >> 4) * 8;   // A[m=lane&15][k=quad*8+j]
      bf16x8 af[2], bfr[2];
      af[0]  = *(const bf16x8*)&As[32 * wm +      (lane & 15)][ks];
      af[1]  = *(const bf16x8*)&As[32 * wm + 16 + (lane & 15)][ks];
      bfr[0] = *(const bf16x8*)&Bs[32 * wn +      (lane & 15)][ks];
      bfr[1] = *(const bf16x8*)&Bs[32 * wn + 16 + (lane & 15)][ks];
      #pragma unroll
      for (int im = 0; im < 2; ++im)
        #pragma unroll
        for (int in = 0; in < 2; ++in)
          acc[im][in] = __builtin_amdgcn_mfma_f32_16x16x32_bf16(
              af[im], bfr[in], acc[im][in], 0, 0, 0);
    }
    __syncthreads();
  }

  // epilogue: C row=(lane>>4)*4+reg, col=lane&15  [guide-verified mapping]
  #pragma unroll
  for (int in = 0; in < 2; ++in) {
    const int col = n0 + 32 * wn + 16 * in + (lane & 15);
    const float bv = bias[col];
    #pragma unroll
    for (int im = 0; im < 2; ++im) {
      const int rbase = m0 + 32 * wm + 16 * im + (lane >> 4) * 4;
      #pragma unroll
      for (int q = 0; q < 4; ++q)
        C[(size_t)(rbase + q) * DIM + col] = acc[im][in][q] + bv;
    }
  }
}

// ---------------------------------------------------------------------------
// Persistent recurrence: 128 WGs x 256 threads. WG k owns rows [16k, 16k+16).
// Wave w owns rows i0+4w..+3; lane l owns cols [32l, 32l+32) held in VGPRs.
// State exchange: tagged u64 (float<<32 | step) relaxed agent atomics,
// double-buffered by parity. cummax fused as per-row running max.
// ctx_proj is read from d_out row t-1 and overwritten with s_t (same thread).
// ---------------------------------------------------------------------------
__global__ __launch_bounds__(256, 1) void recur(const float* __restrict__ W,
                                                const float* __restrict__ ce,
                                                float* __restrict__ out,
                                                u64* __restrict__ pairs) {
  __shared__ __align__(16) float st[DIM];
  const int tid = threadIdx.x;
  const int w = tid >> 6, l = tid & 63;
  const int i0 = blockIdx.x * 16;

  // W_state slab into registers: 4 rows x 32 cols fp32 per lane
  float wreg[4][32];
  #pragma unroll
  for (int r2 = 0; r2 < 4; ++r2) {
    const float* wp = W + (size_t)(i0 + 4 * w + r2) * W2 + 32 * l;
    #pragma unroll
    for (int j = 0; j < 8; ++j) {
      float4 v = ((const float4*)wp)[j];
      wreg[r2][4 * j + 0] = v.x; wreg[r2][4 * j + 1] = v.y;
      wreg[r2][4 * j + 2] = v.z; wreg[r2][4 * j + 3] = v.w;
    }
  }

  const int myrow = i0 + 4 * w + l;  // valid when l < 4
  float hcm = -3.0e38f;              // running cummax
  u64* b0 = pairs;
  u64* b1 = pairs + DIM;
  const int base = tid * 8;

  for (int t = 1; t <= S_LEN; ++t) {
    // prefetch this step's ce / ctx_proj (independent of the poll)
    float cev = 0.f, cxv = 0.f;
    if (l < 4) {
      cev = ce[(size_t)(t - 1) * DIM + myrow];
      cxv = out[(size_t)(t - 1) * DIM + myrow];
    }

    // poll: all 2048 tags of s_{t-1} in buf[(t-1)&1]
    u64* src = ((t - 1) & 1) ? b1 : b0;
    const u32 want = (u32)(t - 1);
    u64 v[8];
    #pragma unroll
    for (int q = 0; q < 8; ++q)
      v[q] = __hip_atomic_load(&src[base + q], __ATOMIC_RELAXED,
                               __HIP_MEMORY_SCOPE_AGENT);
    for (;;) {
      u32 bad = 0;
      #pragma unroll
      for (int q = 0; q < 8; ++q)
        bad |= ((u32)v[q] != want) ? (1u << q) : 0u;
      if (!bad) break;
      #pragma unroll
      for (int q = 0; q < 8; ++q)
        if ((bad >> q) & 1u)
          v[q] = __hip_atomic_load(&src[base + q], __ATOMIC_RELAXED,
                                   __HIP_MEMORY_SCOPE_AGENT);
    }

    __syncthreads();  // prior-iteration LDS reads complete
    // XOR-swizzled store: slot(i) = i ^ (((i>>5)&7)<<2)  -> conflict-free reads
    #pragma unroll
    for (int q = 0; q < 8; ++q) {
      int i = base + q;
      st[i ^ (((i >> 5) & 7) << 2)] = __uint_as_float((u32)(v[q] >> 32));
    }
    __syncthreads();

    // y partial: 4 rows x 32 cols per lane
    float a0 = 0.f, a1 = 0.f, a2 = 0.f, a3 = 0.f;
    #pragma unroll
    for (int jj = 0; jj < 8; ++jj) {
      const float4 sv = *(const float4*)&st[32 * l + 4 * (jj ^ (l & 7))];
      a0 += wreg[0][4*jj]*sv.x + wreg[0][4*jj+1]*sv.y + wreg[0][4*jj+2]*sv.z + wreg[0][4*jj+3]*sv.w;
      a1 += wreg[1][4*jj]*sv.x + wreg[1][4*jj+1]*sv.y + wreg[1][4*jj+2]*sv.z + wreg[1][4*jj+3]*sv.w;
      a2 += wreg[2][4*jj]*sv.x + wreg[2][4*jj+1]*sv.y + wreg[2][4*jj+2]*sv.z + wreg[2][4*jj+3]*sv.w;
      a3 += wreg[3][4*jj]*sv.x + wreg[3][4*jj+1]*sv.y + wreg[3][4*jj+2]*sv.z + wreg[3][4*jj+3]*sv.w;
    }

    // 64-lane butterfly reduce (all lanes end with row sums)
    #pragma unroll
    for (int m = 1; m < 64; m <<= 1) {
      a0 += __shfl_xor(a0, m, 64);
      a1 += __shfl_xor(a1, m, 64);
      a2 += __shfl_xor(a2, m, 64);
      a3 += __shfl_xor(a3, m, 64);
    }

    if (l < 4) {
      float y = (l == 0 ? a0 : l == 1 ? a1 : l == 2 ? a2 : a3) + cxv;
      hcm = fmaxf(hcm, cev);
      float s = hcm * (1.0f / (1.0f + __expf(-y)));
      out[(size_t)(t - 1) * DIM + myrow] = s;
      if (t == S_LEN) out[(size_t)S_LEN * DIM + myrow] = s;
      u64* dst = (t & 1) ? b1 : b0;
      u64 pk = ((u64)__float_as_uint(s) << 32) | (u64)(u32)t;
      __hip_atomic_store(&dst[myrow], pk, __ATOMIC_RELAXED,
                         __HIP_MEMORY_SCOPE_AGENT);
    }
  }
}

// ---------------------------------------------------------------------------
extern "C" void kernel_launch(void* const* d_in, const int* in_sizes, int n_in,
                              void* d_out, int out_size, void* d_ws, size_t ws_size,
                              hipStream_t stream) {
  const float* ce = (const float*)d_in[0];
  const float* W  = (const float*)d_in[1];
  const float* b  = (const float*)d_in[2];
  float* out = (float*)d_out;
  u64* pairs = (u64*)d_ws;   // 2 * 2048 * 8B = 32 KB

  hipLaunchKernelGGL(init_pairs, dim3(16), dim3(256), 0, stream, pairs);
  hipLaunchKernelGGL(gemm_ctx, dim3(DIM / 64, S_LEN / 64), dim3(256), 0, stream,
                     ce, W, b, out);
  hipLaunchKernelGGL(recur, dim3(128), dim3(256), 0, stream, W, ce, out, pairs);
}

// Round 2
// 20213.853 us; speedup vs baseline: 1.4145x; 1.4145x over previous
//
#include <hip/hip_runtime.h>
#include <stdint.h>

#define S_LEN 8192
#define DIM   2048
#define W2    4096   // W row length = 2*DIM

typedef __attribute__((ext_vector_type(8))) __bf16 bf16x8;
typedef __attribute__((ext_vector_type(4))) float  floatx4;
typedef unsigned long long u64;
typedef unsigned int       u32;

// ---------------------------------------------------------------------------
// Init: tag buffers. buf0 = s_0 = -1.0 with tag 0; buf1 tag 0 (never matches
// its first expected tag 1, so readers spin until written).
// ---------------------------------------------------------------------------
__global__ void init_pairs(u64* __restrict__ pairs) {
  int i = blockIdx.x * 256 + threadIdx.x;
  if (i < 2 * DIM) {
    pairs[i] = ((u64)__float_as_uint(-1.0f) << 32) | 0ull;
  }
}

// ---------------------------------------------------------------------------
// GEMM: C[m][n] = sum_k A[m][k] * W[n*4096 + 2048 + k] + b[n]
// (unchanged from R1 — correct, and small vs the recurrence)
// ---------------------------------------------------------------------------
__device__ inline bf16x8 pack_bf8(float4 a, float4 b) {
  bf16x8 h;
  h[0] = (__bf16)a.x; h[1] = (__bf16)a.y; h[2] = (__bf16)a.z; h[3] = (__bf16)a.w;
  h[4] = (__bf16)b.x; h[5] = (__bf16)b.y; h[6] = (__bf16)b.z; h[7] = (__bf16)b.w;
  return h;
}

__global__ __launch_bounds__(256) void gemm_ctx(const float* __restrict__ A,
                                                const float* __restrict__ W,
                                                const float* __restrict__ bias,
                                                float* __restrict__ C) {
  __shared__ __bf16 As[64][72];
  __shared__ __bf16 Bs[64][72];
  const int tid  = threadIdx.x;
  const int m0   = blockIdx.y * 64;
  const int n0   = blockIdx.x * 64;
  const int w    = tid >> 6;
  const int lane = tid & 63;
  const int wm   = w >> 1, wn = w & 1;
  const int r    = tid >> 2;
  const int seg  = tid & 3;

  floatx4 acc[2][2] = {};

  for (int k0 = 0; k0 < DIM; k0 += 64) {
    {
      const float* pa = A + (size_t)(m0 + r) * DIM + k0 + seg * 16;
      const float* pb = W + (size_t)(n0 + r) * W2 + DIM + k0 + seg * 16;
      float4 a0 = ((const float4*)pa)[0], a1 = ((const float4*)pa)[1];
      float4 a2 = ((const float4*)pa)[2], a3 = ((const float4*)pa)[3];
      float4 b0 = ((const float4*)pb)[0], b1 = ((const float4*)pb)[1];
      float4 b2 = ((const float4*)pb)[2], b3 = ((const float4*)pb)[3];
      *(bf16x8*)&As[r][seg * 16]     = pack_bf8(a0, a1);
      *(bf16x8*)&As[r][seg * 16 + 8] = pack_bf8(a2, a3);
      *(bf16x8*)&Bs[r][seg * 16]     = pack_bf8(b0, b1);
      *(bf16x8*)&Bs[r][seg * 16 + 8] = pack_bf8(b2, b3);
    }
    __syncthreads();
    #pragma unroll
    for (int kk = 0; kk < 64; kk += 32) {
      const int ks = kk + (lane >> 4) * 8;
      bf16x8 af[2], bfr[2];
      af[0]  = *(const bf16x8*)&As[32 * wm +      (lane & 15)][ks];
      af[1]  = *(const bf16x8*)&As[32 * wm + 16 + (lane & 15)][ks];
      bfr[0] = *(const bf16x8*)&Bs[32 * wn +      (lane & 15)][ks];
      bfr[1] = *(const bf16x8*)&Bs[32 * wn + 16 + (lane & 15)][ks];
      #pragma unroll
      for (int im = 0; im < 2; ++im)
        #pragma unroll
        for (int in = 0; in < 2; ++in)
          acc[im][in] = __builtin_amdgcn_mfma_f32_16x16x32_bf16(
              af[im], bfr[in], acc[im][in], 0, 0, 0);
    }
    __syncthreads();
  }

  #pragma unroll
  for (int in = 0; in < 2; ++in) {
    const int col = n0 + 32 * wn + 16 * in + (lane & 15);
    const float bv = bias[col];
    #pragma unroll
    for (int im = 0; im < 2; ++im) {
      const int rbase = m0 + 32 * wm + 16 * im + (lane >> 4) * 4;
      #pragma unroll
      for (int q = 0; q < 4; ++q)
        C[(size_t)(rbase + q) * DIM + col] = acc[im][in][q] + bv;
    }
  }
}

// ---------------------------------------------------------------------------
// Persistent recurrence v2: 64 WGs x 512 threads (8 waves). WG k owns rows
// [32k, 32k+32); wave w owns rows i0+4w..+3; lane l owns cols [32l,32l+32).
// Changes vs v1:
//   - 64 pollers instead of 128 (half the spin load traffic into MALL, less
//     producer skew)
//   - ce/ctx_proj prefetched ONE STEP AHEAD, issued after poll success, so
//     the HBM miss is never on the poll's vmcnt critical path (same-thread
//     RAW only: each thread reads and later overwrites its own row element)
//   - tag store issued BEFORE the result store (tag is the global critical
//     path); final-state store hoisted out of the loop
// ---------------------------------------------------------------------------
__global__ __launch_bounds__(512, 1) void recur(const float* __restrict__ W,
                                                const float* __restrict__ ce,
                                                float* __restrict__ out,
                                                u64* __restrict__ pairs) {
  __shared__ __align__(16) float st[DIM];
  const int tid = threadIdx.x;
  const int w = tid >> 6, l = tid & 63;
  const int i0 = blockIdx.x * 32;

  // W_state slab into registers: 4 rows x 32 cols fp32 per lane
  float wreg[4][32];
  #pragma unroll
  for (int r2 = 0; r2 < 4; ++r2) {
    const float* wp = W + (size_t)(i0 + 4 * w + r2) * W2 + 32 * l;
    #pragma unroll
    for (int j = 0; j < 8; ++j) {
      float4 v = ((const float4*)wp)[j];
      wreg[r2][4 * j + 0] = v.x; wreg[r2][4 * j + 1] = v.y;
      wreg[r2][4 * j + 2] = v.z; wreg[r2][4 * j + 3] = v.w;
    }
  }

  const int myrow = i0 + 4 * w + l;  // valid when l < 4
  const bool owner = (l < 4);
  float hcm = -3.0e38f;              // running cummax
  float s_last = 0.f;
  u64* b0 = pairs;
  u64* b1 = pairs + DIM;
  const int base = tid * 4;          // 512 threads x 4 entries = 2048
  // LDS store slot base (XOR swizzle, consistent with the rotated read)
  const int slot4 = (4 * tid) ^ (((tid >> 3) & 7) << 2);

  // step-1 operands (prefetched before the loop)
  float cev = 0.f, cxv = 0.f;
  if (owner) {
    cev = ce[myrow];
    cxv = out[myrow];
  }

  for (int t = 1; t <= S_LEN; ++t) {
    // ---- poll: all 2048 tags of s_{t-1} in buf[(t-1)&1] ----
    u64* src = ((t - 1) & 1) ? b1 : b0;
    const u32 want = (u32)(t - 1);
    u64 v[4];
    #pragma unroll
    for (int q = 0; q < 4; ++q)
      v[q] = __hip_atomic_load(&src[base + q], __ATOMIC_RELAXED,
                               __HIP_MEMORY_SCOPE_AGENT);
    for (;;) {
      u32 bad = 0;
      #pragma unroll
      for (int q = 0; q < 4; ++q)
        bad |= ((u32)v[q] != want) ? (1u << q) : 0u;
      if (!bad) break;
      #pragma unroll
      for (int q = 0; q < 4; ++q)
        if ((bad >> q) & 1u)
          v[q] = __hip_atomic_load(&src[base + q], __ATOMIC_RELAXED,
                                   __HIP_MEMORY_SCOPE_AGENT);
    }

    // ---- issue NEXT step's stream loads now (resolve during next poll) ----
    float ncev = 0.f, ncxv = 0.f;
    if (owner && t < S_LEN) {
      ncev = ce[(size_t)t * DIM + myrow];
      ncxv = out[(size_t)t * DIM + myrow];
    }

    __syncthreads();  // prior-iteration LDS reads complete
    {
      float4 sv4;
      sv4.x = __uint_as_float((u32)(v[0] >> 32));
      sv4.y = __uint_as_float((u32)(v[1] >> 32));
      sv4.z = __uint_as_float((u32)(v[2] >> 32));
      sv4.w = __uint_as_float((u32)(v[3] >> 32));
      *(float4*)&st[slot4] = sv4;
    }
    __syncthreads();

    // ---- y partial: 4 rows x 32 cols per lane ----
    float a0 = 0.f, a1 = 0.f, a2 = 0.f, a3 = 0.f;
    #pragma unroll
    for (int jj = 0; jj < 8; ++jj) {
      const float4 sv = *(const float4*)&st[32 * l + 4 * (jj ^ (l & 7))];
      a0 += wreg[0][4*jj]*sv.x + wreg[0][4*jj+1]*sv.y + wreg[0][4*jj+2]*sv.z + wreg[0][4*jj+3]*sv.w;
      a1 += wreg[1][4*jj]*sv.x + wreg[1][4*jj+1]*sv.y + wreg[1][4*jj+2]*sv.z + wreg[1][4*jj+3]*sv.w;
      a2 += wreg[2][4*jj]*sv.x + wreg[2][4*jj+1]*sv.y + wreg[2][4*jj+2]*sv.z + wreg[2][4*jj+3]*sv.w;
      a3 += wreg[3][4*jj]*sv.x + wreg[3][4*jj+1]*sv.y + wreg[3][4*jj+2]*sv.z + wreg[3][4*jj+3]*sv.w;
    }

    // ---- 64-lane butterfly reduce ----
    #pragma unroll
    for (int m = 1; m < 64; m <<= 1) {
      a0 += __shfl_xor(a0, m, 64);
      a1 += __shfl_xor(a1, m, 64);
      a2 += __shfl_xor(a2, m, 64);
      a3 += __shfl_xor(a3, m, 64);
    }

    if (owner) {
      float y = (l == 0 ? a0 : l == 1 ? a1 : l == 2 ? a2 : a3) + cxv;
      hcm = fmaxf(hcm, cev);
      float s = hcm * (1.0f / (1.0f + __expf(-y)));
      // tag store FIRST — it is the critical path for every other WG
      u64* dst = (t & 1) ? b1 : b0;
      u64 pk = ((u64)__float_as_uint(s) << 32) | (u64)(u32)t;
      __hip_atomic_store(&dst[myrow], pk, __ATOMIC_RELAXED,
                         __HIP_MEMORY_SCOPE_AGENT);
      out[(size_t)(t - 1) * DIM + myrow] = s;
      s_last = s;
    }
    cev = ncev;
    cxv = ncxv;
  }

  if (owner) out[(size_t)S_LEN * DIM + myrow] = s_last;
}

// ---------------------------------------------------------------------------
extern "C" void kernel_launch(void* const* d_in, const int* in_sizes, int n_in,
                              void* d_out, int out_size, void* d_ws, size_t ws_size,
                              hipStream_t stream) {
  const float* ce = (const float*)d_in[0];
  const float* W  = (const float*)d_in[1];
  const float* b  = (const float*)d_in[2];
  float* out = (float*)d_out;
  u64* pairs = (u64*)d_ws;   // 2 * 2048 * 8B = 32 KB

  hipLaunchKernelGGL(init_pairs, dim3(16), dim3(256), 0, stream, pairs);
  hipLaunchKernelGGL(gemm_ctx, dim3(DIM / 64, S_LEN / 64), dim3(256), 0, stream,
                     ce, W, b, out);
  hipLaunchKernelGGL(recur, dim3(64), dim3(512), 0, stream, W, ce, out, pairs);
}